// Round 7
// baseline (699.444 us; speedup 1.0000x reference)
//
#include <hip/hip_runtime.h>

// RNN_Model: biLSTM (T=300,B=4096,D=39,H1=35,H2=30) + FC(50,40,2)
// Round 11 (resubmit; prior bench was a container infra failure):
//  lstm: single merged panel per step: x[0,40)|h1[40,75)|h2[75,105)|pad[105,136).
//    L1 B-frags unchanged (k 0..95, zeros over h2 region); L2 B-frags unchanged
//    (panel col = 40 + old k2) read at arow+40. Kills the duplicate h1 write,
//    halves zero-init, LDS 13.3->8.7KB. L2 pad lanes (u=30,31) compute exact 0
//    -> h2s cols 30,31 now deterministically zero (needed by fc).
//  fc: register-direct fc1 — the 16x16x32 A-frag layout (row=lm, k=oct*8)
//    IS the h2s row layout, so fc1 A-frags are one coalesced dwordx4 per lane
//    per operand (no 64-row LDS staging). Only fc1->fc2->out transposes touch
//    LDS (2 per-wave [16][72] panels; stride 72 = 2-way banks; zero pads make
//    all overread K-slices exact zeros). fcwprep fc1 frags remapped to
//    K-chunks {fw 0-29, bw 0-29} at 32-row offsets.

#define T_STEPS 300
#define DIN 39
#define H1 35
#define H2 30
#define BATCH 4096
#define FC1N 50
#define FC2N 40

#define PAN_STR 136      // halfs per merged A-panel row (16B-aligned rows)

typedef _Float16 f16;
typedef _Float16 half8 __attribute__((ext_vector_type(8)));
typedef float floatx4 __attribute__((ext_vector_type(4)));

__device__ __forceinline__ float sigf(float x) {
    return __builtin_amdgcn_rcpf(1.0f + __expf(-x));
}
// sig(a)*tanh(b) with a single rcp: (e^{2b}-1) / ((1+e^{-a})(e^{2b}+1)).
// b clamped at 30: tanh(30)==1.0f exactly in f32 (no numeric change).
__device__ __forceinline__ float sig_tanh(float a, float b) {
    float bc = fminf(b, 30.0f);
    float ea = __expf(-a);
    float E  = __expf(2.0f * bc);
    return (E - 1.0f) * __builtin_amdgcn_rcpf((1.0f + ea) * (E + 1.0f));
}

// ---------------- wprep: LSTM weight B-fragments, gate-major (UNCHANGED) ----------------
// frag = dir*60 + (layer==0 ? ug*12+g*3+c : 36 + ug*12+g*3+c)
// L1 k: x[0,39)->k, h1: k-1 for k in[40,75), else 0 (covers h2 region with 0s).
// L2 k2: h1[0,35)|h2[35,65), zero k2>=65 (panel col = 40+k2).
__global__ void wprep_kernel(const float* __restrict__ fw1, const float* __restrict__ bw1,
                             const float* __restrict__ fw2, const float* __restrict__ bw2,
                             f16* __restrict__ bp) {
    int frag = blockIdx.x;        // 0..119
    int lane = threadIdx.x;       // 0..63
    int dir = frag / 60;
    int rem = frag % 60;
    int layer = (rem < 36) ? 0 : 1;
    int r2 = (layer == 0) ? rem : rem - 36;
    int ug = r2 / 12, g = (r2 % 12) / 3, c = r2 % 3;
    int u = ug * 16 + (lane & 15);
    const float* W = (layer == 0) ? (dir ? bw1 : fw1) : (dir ? bw2 : fw2);
    for (int j = 0; j < 8; ++j) {
        int k = c * 32 + (lane >> 4) * 8 + j;
        float v = 0.0f;
        if (layer == 0) {
            if (u < H1) {
                int kr = (k < 39) ? k : ((k >= 40 && k < 75) ? k - 1 : -1);
                if (kr >= 0) v = W[kr * (4 * H1) + g * H1 + u];
            }
        } else {
            if (u < H2 && k < 65) v = W[k * (4 * H2) + g * H2 + u];
        }
        bp[(size_t)frag * 512 + lane * 8 + j] = (f16)v;
    }
}

// ---------------- fcwprep: FC weight B-fragments ----------------------------------------
// f 0..7: fc1 (tile 0..3, chunk 0..1) — K map: chunk0 = fw rows 0-29 (+2 zero),
//   chunk1 = bw rows 30-59 (+2 zero) — matches register-direct h2s A-frags.
// f 8..13: fc2 (tile 0..2, chunks at K 0/32, k<50 real); 14..15: out (k<40 real).
__global__ void fcwprep_kernel(const float* __restrict__ Wf1, const float* __restrict__ Wf2,
                               const float* __restrict__ Wo, f16* __restrict__ fcp) {
    int f = blockIdx.x;
    int lane = threadIdx.x;
    int lm = lane & 15, oct = lane >> 4;
    for (int j = 0; j < 8; ++j) {
        float v = 0.0f;
        if (f < 8) {
            int tile = f >> 1, chunk = f & 1;
            int n = tile * 16 + lm;
            int kl = oct * 8 + j;                // 0..31 within the chunk
            if (n < FC1N && kl < 30) v = Wf1[(chunk * 30 + kl) * FC1N + n];
        } else if (f < 14) {
            int g = f - 8, tile = g >> 1, chunk = g & 1;
            int n = tile * 16 + lm;
            int k = chunk * 32 + oct * 8 + j;
            if (n < FC2N && k < FC1N) v = Wf2[k * FC2N + n];
        } else {
            int chunk = f - 14;
            int k = chunk * 32 + oct * 8 + j;
            if (lm < 2 && k < FC2N) v = Wo[k * 2 + lm];
        }
        fcp[(size_t)f * 512 + lane * 8 + j] = (f16)v;
    }
}

// ---------------- fused 2-layer LSTM -----------------------------------------------------
__global__ __launch_bounds__(320, 3) void lstm_fused(
    const float* __restrict__ x, const f16* __restrict__ bp,
    const float* __restrict__ fb1, const float* __restrict__ bb1,
    const float* __restrict__ fb2, const float* __restrict__ bb2,
    f16* __restrict__ h2s)
{
    __shared__ f16 pan[2][16 * PAN_STR];  // x[0,40) | h1[40,75) | h2[75,105) | 0[105,136)

    const int tid = threadIdx.x;
    const int b0  = blockIdx.x * 16;
    const int dir = blockIdx.y;
    const int wv   = tid >> 6;            // 0..4
    const int lane = tid & 63;
    const int lm = lane & 15, oct = lane >> 4;
    const bool isL2 = (wv >= 3);
    const int ug = isL2 ? (wv - 3) : wv;  // unit group within its layer
    const int u  = ug * 16 + lm;          // this lane's unit
    const int Hn = isL2 ? H2 : H1;
    const float* bias = isL2 ? (dir ? bb2 : fb2) : (dir ? bb1 : fb1);
    const int fragbase = dir * 60 + (isL2 ? 36 : 0) + ug * 12;

    // persistent gate-major B-fragments (one layer's set per wave)
    half8 bf[4][3];
    #pragma unroll
    for (int g = 0; g < 4; ++g)
        #pragma unroll
        for (int c = 0; c < 3; ++c)
            bf[g][c] = *(const half8*)(bp + (size_t)(fragbase + g * 3 + c) * 512 + lane * 8);

    // gate biases (C-init); pad lanes (u>=Hn) get 0 -> their gates compute exact 0
    float zb[4];
    #pragma unroll
    for (int g = 0; g < 4; ++g)
        zb[g] = (u < Hn) ? bias[g * Hn + u] : 0.f;
    float cst[4] = {0.f, 0.f, 0.f, 0.f};  // c-state, rows oct*4+r of unit u

    // running output pointer for L2 waves (t_out moves +-1 per step)
    f16* h2p = h2s + ((size_t)(dir * BATCH + b0 + oct * 4) * T_STEPS
                      + (dir ? (T_STEPS - 1) : 0)) * 32 + u;
    const int h2step = dir ? -32 : 32;

    // zero both panel buffers (h0 = c0 = 0, pads)
    for (int idx = tid; idx < 16 * PAN_STR; idx += 320) {
        pan[0][idx] = (f16)0.f; pan[1][idx] = (f16)0.f;
    }
    __syncthreads();   // zero-init before x staging

    // x staging: 160 threads, thread -> (row sr, quad sq), 4 f32 loads -> 4 f16
    const int sr = tid / 10, sq = tid % 10;
    float xv[4] = {0.f, 0.f, 0.f, 0.f};
    if (tid < 160) {
        int t0 = dir ? (T_STEPS - 1) : 0;
        const float* p0 = x + ((size_t)(b0 + sr) * T_STEPS + t0) * DIN;
        union { f16 h[4]; uint2 u; } pk;
        #pragma unroll
        for (int i = 0; i < 4; ++i) { int k = sq * 4 + i; pk.h[i] = (k < DIN) ? (f16)p0[k] : (f16)0.f; }
        *(uint2*)(&pan[0][sr * PAN_STR + sq * 4]) = pk.u;
        int t1 = dir ? (T_STEPS - 2) : 1;
        const float* p1 = x + ((size_t)(b0 + sr) * T_STEPS + t1) * DIN;
        #pragma unroll
        for (int i = 0; i < 4; ++i) { int k = sq * 4 + i; xv[i] = (k < DIN) ? p1[k] : 0.f; }
    }
    __syncthreads();

    const int arow = lm * PAN_STR + oct * 8 + (isL2 ? 40 : 0);

    // prologue (L1 waves only): z1(0) -> h1(0) into pan[1]
    if (!isL2) {
        floatx4 C[4];
        #pragma unroll
        for (int g = 0; g < 4; ++g) C[g] = (floatx4){zb[g], zb[g], zb[g], zb[g]};
        half8 a0 = *(const half8*)(&pan[0][arow]);
        half8 a1 = *(const half8*)(&pan[0][arow + 32]);
        half8 a2 = *(const half8*)(&pan[0][arow + 64]);
        #pragma unroll
        for (int g = 0; g < 4; ++g) {
            C[g] = __builtin_amdgcn_mfma_f32_16x16x32_f16(a0, bf[g][0], C[g], 0, 0, 0);
            C[g] = __builtin_amdgcn_mfma_f32_16x16x32_f16(a1, bf[g][1], C[g], 0, 0, 0);
            C[g] = __builtin_amdgcn_mfma_f32_16x16x32_f16(a2, bf[g][2], C[g], 0, 0, 0);
        }
        #pragma unroll
        for (int r = 0; r < 4; ++r) {
            float cc = sigf(C[2][r] + 1.0f) * cst[r] + sig_tanh(C[0][r], C[1][r]);
            cst[r] = cc;
            float hh = sig_tanh(C[3][r], cc);
            if (u < H1) {
                int row = oct * 4 + r;
                pan[1][row * PAN_STR + 40 + u] = (f16)hh;
            }
        }
    }
    // x prefetch running pointer: first in-loop load target is t(s=0,+3)
    const float* px = x + ((size_t)(b0 + sr) * T_STEPS
                           + (dir ? (T_STEPS - 4) : 3)) * DIN + sq * 4;
    const int xstep = dir ? -DIN : DIN;
    if (tid < 160) {
        union { f16 h[4]; uint2 u; } pk;
        #pragma unroll
        for (int i = 0; i < 4; ++i) pk.h[i] = (f16)xv[i];
        *(uint2*)(&pan[1][sr * PAN_STR + sq * 4]) = pk.u;
        int t2 = dir ? (T_STEPS - 3) : 2;
        const float* p2 = x + ((size_t)(b0 + sr) * T_STEPS + t2) * DIN;
        #pragma unroll
        for (int i = 0; i < 4; ++i) { int k = sq * 4 + i; xv[i] = (k < DIN) ? p2[k] : 0.f; }
    }
    __syncthreads();
    // invariant at iter s: pan[p] = {x(s+1), h1(s), h2(s-1)}, xv = x(s+2)
    // L1 waves compute z1(s+1); L2 waves compute z2(s).

    for (int s = 0; s < T_STEPS; ++s) {
        const int p = 1 - (s & 1);

        // issue next x loads early (x(s+3); px clamps at the last row)
        float xn[4] = {0.f, 0.f, 0.f, 0.f};
        if (tid < 160) {
            #pragma unroll
            for (int i = 0; i < 4; ++i) { int k = sq * 4 + i; xn[i] = (k < DIN) ? px[i] : 0.f; }
        }
        if (s < T_STEPS - 4) px += xstep;   // stop advancing once clamped

        // ---- MFMA: each wave does its own unit-group's 4 gate tiles ----
        const f16* ap = &pan[p][0];
        floatx4 C[4];
        #pragma unroll
        for (int g = 0; g < 4; ++g) C[g] = (floatx4){zb[g], zb[g], zb[g], zb[g]};
        {
            half8 a0 = *(const half8*)(ap + arow);
            half8 a1 = *(const half8*)(ap + arow + 32);
            half8 a2 = *(const half8*)(ap + arow + 64);
            #pragma unroll
            for (int g = 0; g < 4; ++g) {
                C[g] = __builtin_amdgcn_mfma_f32_16x16x32_f16(a0, bf[g][0], C[g], 0, 0, 0);
                C[g] = __builtin_amdgcn_mfma_f32_16x16x32_f16(a1, bf[g][1], C[g], 0, 0, 0);
                C[g] = __builtin_amdgcn_mfma_f32_16x16x32_f16(a2, bf[g][2], C[g], 0, 0, 0);
            }
        }

        // ---- nonlinearity in registers; write h into pan[1-p] ----
        f16* w = &pan[1 - p][0];
        if (!isL2) {
            #pragma unroll
            for (int r = 0; r < 4; ++r) {
                float cc = sigf(C[2][r] + 1.0f) * cst[r] + sig_tanh(C[0][r], C[1][r]);
                cst[r] = cc;
                float hh = sig_tanh(C[3][r], cc);
                if (u < H1) {
                    int row = oct * 4 + r;
                    w[row * PAN_STR + 40 + u] = (f16)hh;   // h1(s+1), single write
                }
            }
        } else {
            // pad lanes (u=30,31) compute exact 0 -> unconditional writes are safe
            // and give fc deterministic zeros in h2s cols 30,31.
            #pragma unroll
            for (int r = 0; r < 4; ++r) {
                float dd = sigf(C[2][r] + 1.0f) * cst[r] + sig_tanh(C[0][r], C[1][r]);
                cst[r] = dd;
                float gg = sig_tanh(C[3][r], dd);
                int row = oct * 4 + r;
                f16 gv = (f16)gg;
                w[row * PAN_STR + 75 + u] = gv;          // h2(s) (cols 105,106 = pad, 0)
                h2p[(size_t)r * T_STEPS * 32] = gv;      // h2s out (running ptr)
            }
        }
        h2p += h2step;

        // ---- stage x(s+2) into pan[1-p] ----
        if (tid < 160) {
            union { f16 h[4]; uint2 u; } pk;
            #pragma unroll
            for (int i = 0; i < 4; ++i) pk.h[i] = (f16)xv[i];
            *(uint2*)(&pan[1 - p][sr * PAN_STR + sq * 4]) = pk.u;
            #pragma unroll
            for (int i = 0; i < 4; ++i) xv[i] = xn[i];
        }
        __syncthreads();   // the single per-step barrier
    }
}

// ---------------- FC stack: register-direct fc1, small LDS transposes --------------------
// h2s layout [dir][b][t][32] (cols 30,31 zero); rid = b*T + t.
// fc1 A-frag (row=lm, k=oct*8..+7) == one dwordx4 of h2s per lane per operand.
// Per-wave panels [16][72]: zero-padded so every overread K-slice is exact 0.
__global__ __launch_bounds__(256) void fc_kernel(
    const f16* __restrict__ h2s, const f16* __restrict__ fcp,
    const float* __restrict__ bf1, const float* __restrict__ bf2,
    const float* __restrict__ bo, float* __restrict__ out)
{
    __shared__ f16 apf[4][2][16 * 72];   // [wave][pa|pb][...]
    const int tid = threadIdx.x;
    const int wv = tid >> 6, lane = tid & 63;
    const int lm = lane & 15, oct = lane >> 4;
    f16* pa = &apf[wv][0][0];
    f16* pb = &apf[wv][1][0];

    // zero both panels once (pads stay 0; real cols overwritten each iter)
    {
        uint* z = (uint*)pa;             // 2*16*72 halfs = 1152 dwords
        for (int i = lane; i < 1152; i += 64) z[i] = 0u;
    }

    half8 wf[16];
    #pragma unroll
    for (int f = 0; f < 16; ++f)
        wf[f] = *(const half8*)(fcp + (size_t)f * 512 + lane * 8);

    const int ar = lm * 72 + oct * 8;
    const size_t base = (size_t)blockIdx.x * 256 + wv * 64;
    const size_t bwoff = (size_t)BATCH * T_STEPS * 32;

    union U8 { uint4 u; half8 h; };
    const f16* gp = h2s + (base + lm) * 32 + oct * 8;
    U8 va, vb;
    va.u = *(const uint4*)gp;
    vb.u = *(const uint4*)(gp + bwoff);

    for (int it = 0; it < 4; ++it) {
        half8 a0 = va.h, a1 = vb.h;
        if (it < 3) {   // prefetch next 16 rows; hides under the MFMA chain
            const f16* gn = gp + (size_t)(it + 1) * 16 * 32;
            va.u = *(const uint4*)gn;
            vb.u = *(const uint4*)(gn + bwoff);
        }

        // fc1: [16x60] @ [60x50] + relu (A from registers)
        floatx4 C[4];
        #pragma unroll
        for (int t = 0; t < 4; ++t) {
            int col = t * 16 + lm;
            float b = (col < FC1N) ? bf1[col] : 0.f;
            C[t] = (floatx4){b, b, b, b};
            C[t] = __builtin_amdgcn_mfma_f32_16x16x32_f16(a0, wf[t * 2 + 0], C[t], 0, 0, 0);
            C[t] = __builtin_amdgcn_mfma_f32_16x16x32_f16(a1, wf[t * 2 + 1], C[t], 0, 0, 0);
        }
        #pragma unroll
        for (int t = 0; t < 4; ++t) {
            int col = t * 16 + lm;   // cols >= 50 write exact 0 (b=0, B cols zero)
            #pragma unroll
            for (int r = 0; r < 4; ++r)
                pa[(oct * 4 + r) * 72 + col] = (f16)fmaxf(C[t][r], 0.f);
        }

        // fc2: [16x50] @ [50x40] + relu
        half8 b0 = *(const half8*)(pa + ar);
        half8 b1 = *(const half8*)(pa + ar + 32);   // oct=3 reads cols 56-63 = 0
        floatx4 D[3];
        #pragma unroll
        for (int t = 0; t < 3; ++t) {
            int col = t * 16 + lm;
            float b = (col < FC2N) ? bf2[col] : 0.f;
            D[t] = (floatx4){b, b, b, b};
            D[t] = __builtin_amdgcn_mfma_f32_16x16x32_f16(b0, wf[8 + t * 2 + 0], D[t], 0, 0, 0);
            D[t] = __builtin_amdgcn_mfma_f32_16x16x32_f16(b1, wf[8 + t * 2 + 1], D[t], 0, 0, 0);
        }
        #pragma unroll
        for (int t = 0; t < 3; ++t) {
            int col = t * 16 + lm;   // cols >= 40 write exact 0
            #pragma unroll
            for (int r = 0; r < 4; ++r)
                pb[(oct * 4 + r) * 72 + col] = (f16)fmaxf(D[t][r], 0.f);
        }

        // out: [16x40] @ [40x2]
        half8 c0 = *(const half8*)(pb + ar);
        half8 c1 = *(const half8*)(pb + ar + 32);
        float b = (lm < 2) ? bo[lm] : 0.f;
        floatx4 E = (floatx4){b, b, b, b};
        E = __builtin_amdgcn_mfma_f32_16x16x32_f16(c0, wf[14], E, 0, 0, 0);
        E = __builtin_amdgcn_mfma_f32_16x16x32_f16(c1, wf[15], E, 0, 0, 0);
        if (lm < 2) {
            const size_t rid0 = base + it * 16;
            #pragma unroll
            for (int r = 0; r < 4; ++r)
                out[(rid0 + oct * 4 + r) * 2 + lm] = E[r];
        }
    }
}

extern "C" void kernel_launch(void* const* d_in, const int* in_sizes, int n_in,
                              void* d_out, int out_size, void* d_ws, size_t ws_size,
                              hipStream_t stream) {
    const float* x     = (const float*)d_in[0];
    const float* fw_W1 = (const float*)d_in[1];
    const float* fw_b1 = (const float*)d_in[2];
    const float* fw_W2 = (const float*)d_in[3];
    const float* fw_b2 = (const float*)d_in[4];
    const float* bw_W1 = (const float*)d_in[5];
    const float* bw_b1 = (const float*)d_in[6];
    const float* bw_W2 = (const float*)d_in[7];
    const float* bw_b2 = (const float*)d_in[8];
    const float* Wf1   = (const float*)d_in[9];
    const float* bf1   = (const float*)d_in[10];
    const float* Wf2   = (const float*)d_in[11];
    const float* bf2   = (const float*)d_in[12];
    const float* Wo    = (const float*)d_in[13];
    const float* bo    = (const float*)d_in[14];
    float* outp = (float*)d_out;

    // ws: h2s [2][4096][300][32] f16 | bp 120*512 f16 | fcp 16*512 f16
    f16* h2s = (f16*)d_ws;
    f16* bp  = h2s + (size_t)2 * BATCH * T_STEPS * 32;
    f16* fcp = bp + (size_t)120 * 512;

    wprep_kernel<<<120, 64, 0, stream>>>(fw_W1, bw_W1, fw_W2, bw_W2, bp);
    fcwprep_kernel<<<16, 64, 0, stream>>>(Wf1, Wf2, Wo, fcp);

    dim3 gl(BATCH / 16, 2);   // (256, 2) = 512 blocks -> 2 blocks/CU, 10 waves/CU
    lstm_fused<<<gl, 320, 0, stream>>>(x, bp, fw_b1, bw_b1, fw_b2, bw_b2, h2s);

    fc_kernel<<<(BATCH * T_STEPS) / 256, 256, 0, stream>>>(
        h2s, fcp, bf1, bf2, bo, outp);
}